// Round 1
// baseline (139.330 us; speedup 1.0000x reference)
//
#include <hip/hip_runtime.h>

// SpatialTransformer: bilinear sampling of moving_image [B,H,W,C] at
// coords (deformation + meshgrid), zero-padded by 1, clip semantics per ref.
// B=16, H=512, W=512, C=16, fp32 in/out.

#define B_ 16
#define H_ 512
#define W_ 512
#define C_ 16

__global__ __launch_bounds__(256) void st_bilinear_kernel(
    const float* __restrict__ img,   // [B,H,W,C]
    const float* __restrict__ def,   // [B,H,W,2]
    float* __restrict__ out)         // [B,H,W,C]
{
    int tid = blockIdx.x * blockDim.x + threadIdx.x;   // [0, B*H*W*4)
    int p  = tid >> 2;            // pixel index in [0, B*H*W)
    int cq = (tid & 3) << 2;      // channel offset: 0,4,8,12

    int xw = p & 511;             // W index
    int y  = (p >> 9) & 511;      // H index
    int b  = p >> 18;             // batch index

    // deformation (2 floats per pixel)
    float2 d = *reinterpret_cast<const float2*>(def + ((size_t)p << 1));

    // coords in padded frame (pad=1)
    float xf = d.x + (float)xw + 1.0f;
    float yf = d.y + (float)y  + 1.0f;

    int x0 = (int)floorf(xf);
    int y0 = (int)floorf(yf);
    int x1 = min(max(x0 + 1, 0), W_ + 1);
    int y1 = min(max(y0 + 1, 0), H_ + 1);
    x0 = min(max(x0, 0), W_ + 1);
    y0 = min(max(y0, 0), H_ + 1);

    float dx = (float)x1 - xf;
    float dy = (float)y1 - yf;
    float wa = dx * dy;
    float wb = dx * (1.0f - dy);
    float wc = (1.0f - dx) * dy;
    float wd = (1.0f - dx) * (1.0f - dy);

    const float* base = img + ((size_t)b << 22);  // b * H*W*C

    // padded image: im[yi][xi] = img[yi-1][xi-1] if 1<=yi<=H && 1<=xi<=W else 0
    auto load4 = [&](int yi, int xi) -> float4 {
        if (yi >= 1 && yi <= H_ && xi >= 1 && xi <= W_) {
            size_t off = ((size_t)(((yi - 1) << 9) | (xi - 1)) << 4) + cq;
            return *reinterpret_cast<const float4*>(base + off);
        }
        return make_float4(0.f, 0.f, 0.f, 0.f);
    };

    float4 Ia = load4(y0, x0);
    float4 Ib = load4(y1, x0);
    float4 Ic = load4(y0, x1);
    float4 Id = load4(y1, x1);

    float4 r;
    r.x = wa * Ia.x + wb * Ib.x + wc * Ic.x + wd * Id.x;
    r.y = wa * Ia.y + wb * Ib.y + wc * Ic.y + wd * Id.y;
    r.z = wa * Ia.z + wb * Ib.z + wc * Ic.z + wd * Id.z;
    r.w = wa * Ia.w + wb * Ib.w + wc * Ic.w + wd * Id.w;

    *reinterpret_cast<float4*>(out + ((size_t)p << 4) + cq) = r;
}

extern "C" void kernel_launch(void* const* d_in, const int* in_sizes, int n_in,
                              void* d_out, int out_size, void* d_ws, size_t ws_size,
                              hipStream_t stream) {
    const float* img = (const float*)d_in[0];   // moving_image [B,H,W,C]
    const float* def = (const float*)d_in[1];   // deformation  [B,H,W,2]
    float* out = (float*)d_out;

    const int total_threads = B_ * H_ * W_ * 4;   // one thread per (pixel, channel-quad)
    const int block = 256;
    const int grid = total_threads / block;       // 65536

    st_bilinear_kernel<<<grid, block, 0, stream>>>(img, def, out);
}

// Round 2
// 94.731 us; speedup vs baseline: 1.4708x; 1.4708x over previous
//
#include <hip/hip_runtime.h>

// SpatialTransformer bilinear sampling, B=16 H=512 W=512 C=16 fp32.
// Round 2: branchless clamp+mask gathers, 2 row-adjacent pixels per thread
// (MLP + L1 window overlap), nontemporal store for out / load for def
// (keep the 268MB image resident in the 256MB L3 across replays).

#define H_ 512
#define W_ 512

typedef float v2f __attribute__((ext_vector_type(2)));
typedef float v4f __attribute__((ext_vector_type(4)));

__device__ __forceinline__ v4f bilerp_quad(const float* __restrict__ base,
                                           int cq, int xw, int y, v2f d)
{
    // coords in padded frame (pad=1), exactly per reference
    float xf = d.x + (float)xw + 1.0f;
    float yf = d.y + (float)y  + 1.0f;

    int x0 = (int)floorf(xf);
    int y0 = (int)floorf(yf);
    int x1 = min(max(x0 + 1, 0), W_ + 1);
    int y1 = min(max(y0 + 1, 0), H_ + 1);
    x0 = min(max(x0, 0), W_ + 1);
    y0 = min(max(y0, 0), H_ + 1);

    float dx = (float)x1 - xf;
    float dy = (float)y1 - yf;

    // padded index i maps to real pixel i-1 iff 1 <= i <= 512, else zero pad
    float vx0 = (x0 >= 1 && x0 <= W_) ? 1.0f : 0.0f;
    float vx1 = (x1 >= 1 && x1 <= W_) ? 1.0f : 0.0f;
    float vy0 = (y0 >= 1 && y0 <= H_) ? 1.0f : 0.0f;
    float vy1 = (y1 >= 1 && y1 <= H_) ? 1.0f : 0.0f;

    int xc0 = min(max(x0, 1), W_) - 1;
    int xc1 = min(max(x1, 1), W_) - 1;
    int yc0 = min(max(y0, 1), H_) - 1;
    int yc1 = min(max(y1, 1), H_) - 1;

    const float* pa = base + ((size_t)((yc0 << 9) | xc0) << 4) + cq;
    const float* pb = base + ((size_t)((yc1 << 9) | xc0) << 4) + cq;
    const float* pc = base + ((size_t)((yc0 << 9) | xc1) << 4) + cq;
    const float* pd = base + ((size_t)((yc1 << 9) | xc1) << 4) + cq;

    v4f Ia = *reinterpret_cast<const v4f*>(pa);
    v4f Ib = *reinterpret_cast<const v4f*>(pb);
    v4f Ic = *reinterpret_cast<const v4f*>(pc);
    v4f Id = *reinterpret_cast<const v4f*>(pd);

    float wa = dx * dy                   * (vx0 * vy0);
    float wb = dx * (1.0f - dy)          * (vx0 * vy1);
    float wc = (1.0f - dx) * dy          * (vx1 * vy0);
    float wd = (1.0f - dx) * (1.0f - dy) * (vx1 * vy1);

    return wa * Ia + wb * Ib + wc * Ic + wd * Id;
}

__global__ __launch_bounds__(256) void st_bilinear2(
    const float* __restrict__ img,   // [B,H,W,C]
    const float* __restrict__ def,   // [B,H,W,2]
    float* __restrict__ out)         // [B,H,W,C]
{
    int tid = blockIdx.x * 256 + threadIdx.x;   // [0, 8388608)
    int cq  = (tid & 3) << 2;                   // channel offset 0,4,8,12
    int pp  = tid >> 2;                         // pixel-pair index
    int xw  = pp & 511;
    int yh  = (pp >> 9) & 255;
    int b   = pp >> 17;
    int y0r = yh << 1;                          // even row
    int p0  = (b << 18) | (y0r << 9) | xw;      // pixel index of row y0r
    int p1  = p0 + W_;                          // pixel index of row y0r+1

    const float* base = img + ((size_t)b << 22);

    v2f d0 = __builtin_nontemporal_load(
        reinterpret_cast<const v2f*>(def + ((size_t)p0 << 1)));
    v2f d1 = __builtin_nontemporal_load(
        reinterpret_cast<const v2f*>(def + ((size_t)p1 << 1)));

    v4f r0 = bilerp_quad(base, cq, xw, y0r,     d0);
    v4f r1 = bilerp_quad(base, cq, xw, y0r + 1, d1);

    __builtin_nontemporal_store(r0, reinterpret_cast<v4f*>(out + ((size_t)p0 << 4) + cq));
    __builtin_nontemporal_store(r1, reinterpret_cast<v4f*>(out + ((size_t)p1 << 4) + cq));
}

extern "C" void kernel_launch(void* const* d_in, const int* in_sizes, int n_in,
                              void* d_out, int out_size, void* d_ws, size_t ws_size,
                              hipStream_t stream) {
    const float* img = (const float*)d_in[0];   // moving_image [B,H,W,C]
    const float* def = (const float*)d_in[1];   // deformation  [B,H,W,2]
    float* out = (float*)d_out;

    const int total_threads = 16 * 512 * 512 * 4 / 2;  // 2 pixels per thread
    const int block = 256;
    const int grid = total_threads / block;            // 32768

    st_bilinear2<<<grid, block, 0, stream>>>(img, def, out);
}